// Round 8
// baseline (11480.950 us; speedup 1.0000x reference)
//
#include <hip/hip_runtime.h>
#include <math.h>

// ---------------------------------------------------------------------------
// Bert_BiLstm_Crf: 2-layer BiLSTM (B=64,T=512,D=768,H=384/dir) -> FC(30) -> Viterbi
// Round 8: 32 streams x 8 WGs (4 batches/stream, 48 units/WG), register-fat
// matvec tile (12u x 24k x 4b => W in 288 VGPRs, LDS reads 4x lower), round-4
// verified sc0 sc1 + flag sync protocol (single phase).
// ---------------------------------------------------------------------------

#define B_    64
#define T_    512
#define D_    768
#define H_    384
#define G4    1536
#define NTAGS 30
#define TC    64
#define NCH   (T_ / TC)     // 8

typedef float f32x4 __attribute__((ext_vector_type(4)));

__device__ __forceinline__ float sigm(float x) { return 1.f / (1.f + expf(-x)); }

// ------------- chunk GEMM (z picks fwd/bwd): pre = A_chunk @ W^T + b1 + b2 --
__global__ __launch_bounds__(256)
void sgemm_pre(const float* __restrict__ A, int t0f, int t0b,
               const float* __restrict__ Wf, const float* __restrict__ Wb,
               const float* __restrict__ b1f, const float* __restrict__ b2f,
               const float* __restrict__ b1b, const float* __restrict__ b2b,
               float* __restrict__ outF, float* __restrict__ outB) {
  const int z = blockIdx.z;
  const int t0 = z ? t0b : t0f;
  const float* __restrict__ W  = z ? Wb  : Wf;
  const float* __restrict__ b1 = z ? b1b : b1f;
  const float* __restrict__ b2 = z ? b2b : b2f;
  float* __restrict__ Cc = z ? outB : outF;

  __shared__ float As[16][128];
  __shared__ float Bs[16][128];
  const int tid = threadIdx.x;
  const int bm = blockIdx.y * 128;
  const int bn = blockIdx.x * 128;
  const int tx = tid & 15;
  const int ty = tid >> 4;

  float acc[8][8];
  #pragma unroll
  for (int i = 0; i < 8; ++i)
    #pragma unroll
    for (int j = 0; j < 8; ++j) acc[i][j] = 0.f;

  for (int k0 = 0; k0 < D_; k0 += 16) {
    #pragma unroll
    for (int s = tid; s < 512; s += 256) {
      int r = s >> 2, k4 = (s & 3) * 4;
      int rl = bm + r;
      const float* arow = A + ((size_t)(rl >> 6) * T_ + t0 + (rl & 63)) * D_;
      float4 va = *(const float4*)(arow + k0 + k4);
      As[k4 + 0][r] = va.x; As[k4 + 1][r] = va.y;
      As[k4 + 2][r] = va.z; As[k4 + 3][r] = va.w;
      float4 vb = *(const float4*)(W + (size_t)(bn + r) * D_ + k0 + k4);
      Bs[k4 + 0][r] = vb.x; Bs[k4 + 1][r] = vb.y;
      Bs[k4 + 2][r] = vb.z; Bs[k4 + 3][r] = vb.w;
    }
    __syncthreads();
    #pragma unroll
    for (int k = 0; k < 16; ++k) {
      float a[8], bv[8];
      *(float4*)(a)      = *(const float4*)&As[k][ty * 4];
      *(float4*)(a + 4)  = *(const float4*)&As[k][64 + ty * 4];
      *(float4*)(bv)     = *(const float4*)&Bs[k][tx * 4];
      *(float4*)(bv + 4) = *(const float4*)&Bs[k][64 + tx * 4];
      #pragma unroll
      for (int i = 0; i < 8; ++i)
        #pragma unroll
        for (int j = 0; j < 8; ++j)
          acc[i][j] += a[i] * bv[j];
    }
    __syncthreads();
  }

  float4 b1l = *(const float4*)(b1 + bn + tx * 4);
  float4 b2l = *(const float4*)(b2 + bn + tx * 4);
  float4 b1h = *(const float4*)(b1 + bn + 64 + tx * 4);
  float4 b2h = *(const float4*)(b2 + bn + 64 + tx * 4);
  float4 bl = {b1l.x + b2l.x, b1l.y + b2l.y, b1l.z + b2l.z, b1l.w + b2l.w};
  float4 bh = {b1h.x + b2h.x, b1h.y + b2h.y, b1h.z + b2h.z, b1h.w + b2h.w};

  #pragma unroll
  for (int i = 0; i < 8; ++i) {
    int r = (i < 4) ? (ty * 4 + i) : (64 + ty * 4 + (i - 4));
    size_t row = (size_t)(bm + r);
    float4 lo = {acc[i][0] + bl.x, acc[i][1] + bl.y, acc[i][2] + bl.z, acc[i][3] + bl.w};
    float4 hi = {acc[i][4] + bh.x, acc[i][5] + bh.y, acc[i][6] + bh.z, acc[i][7] + bh.w};
    *(float4*)(Cc + row * G4 + bn + tx * 4)      = lo;
    *(float4*)(Cc + row * G4 + bn + 64 + tx * 4) = hi;
  }
}

// ---------------- persistent-W LSTM recurrence chunk ------------------------
// 256 WGs (1/CU). stream = bid&31 -> (dir = s&1, 4-batch group bg = s>>1);
// wg = bid>>5 -> 48 hidden units. W block (4 gates x 48 u x k-slice 24) lives
// in 288 VGPRs/thread (1 wave/SIMD => 512-VGPR budget). Per step: matvec
// (acc[12][4]) -> per-row butterfly over 16 k-lanes -> gate LDS exchange ->
// nonlinearity by owner threads -> sc0 sc1 publish -> vmcnt ack -> flag ->
// poll 8 flags -> reload 6KB. Protocol semantics identical to round 4.
template<int LAYER>
__global__ __launch_bounds__(256, 1)
void lstm_chunk(const float* __restrict__ preF, const float* __restrict__ preB,
                const float* __restrict__ whhF, const float* __restrict__ whhB,
                float* __restrict__ hbuf, float* __restrict__ h2cF, float* __restrict__ h2cB,
                float* __restrict__ h_g, float* __restrict__ c_g,
                unsigned* __restrict__ flags, int chunk, unsigned seqBase) {
  const int bid    = blockIdx.x;
  const int stream = bid & 31;          // 0..31
  const int wg     = bid >> 5;          // 0..7
  const int dir    = stream & 1;
  const int bg     = stream >> 1;       // 0..15
  const int tid    = threadIdx.x;
  const int g      = tid >> 6;          // gate (wave) 0..3
  const int lane   = tid & 63;
  const int ks     = lane & 15;         // k-slice id (24 k each)
  const int ug     = lane >> 4;         // unit group 0..3 (12 units each)

  const float* __restrict__ pre = dir ? preB : preF;
  const float* __restrict__ whh = dir ? whhB : whhF;

  __shared__ float h_lds[4 * 448];      // [b][16 slices * 28]
  __shared__ float gLDS[4 * 192];       // [gate][u*4 + b]
  __shared__ float lds_pad[18432];      // force 1 WG/CU

  if (flags[300] == 0xDEADBEEFu) lds_pad[tid] = 1.f;  // keep pad alive

  // ---- W block in registers: rows g*384 + wg*48 + ug*12 + r, k = ks*24 + j ----
  f32x4 W[12][6];
  {
    const float* wsrc = whh + ((size_t)(g * H_ + wg * 48 + ug * 12)) * H_ + ks * 24;
    #pragma unroll
    for (int r = 0; r < 12; ++r)
      #pragma unroll
      for (int jj = 0; jj < 6; ++jj)
        W[r][jj] = *(const f32x4*)(wsrc + (size_t)r * H_ + jj * 4);
  }

  // gate/c ownership: tid<192 -> (u = tid%48, b = tid/48 in [0,4))
  const int own_u = tid % 48;
  const int own_b = tid / 48;
  float c_own = 0.f;
  if (chunk > 0 && tid < 192)
    c_own = c_g[(size_t)(stream * 8 + wg) * 192 + tid];

  float* hg0 = h_g + (size_t)stream * 1536;          // parity 0: 4b x 384u
  float* hg1 = h_g + (size_t)(32 + stream) * 1536;   // parity 1

  // ---- init h_lds (swizzle col = (k/24)*28 + k%24); cross-launch: plain ----
  if (chunk == 0) {
    for (int i = tid; i < 4 * 448; i += 256) h_lds[i] = 0.f;
  } else {
    {
      int f = tid;                     // f4 index 0..383 (384 total)
      int b = f / 96, k4 = (f % 96) * 4;
      float4 v = *(const float4*)(hg0 + b * 384 + k4);
      *(float4*)&h_lds[b * 448 + (k4 / 24) * 28 + (k4 % 24)] = v;
    }
    if (tid < 128) {
      int f = tid + 256;
      int b = f / 96, k4 = (f % 96) * 4;
      float4 v = *(const float4*)(hg0 + b * 384 + k4);
      *(float4*)&h_lds[b * 448 + (k4 / 24) * 28 + (k4 % 24)] = v;
    }
  }
  __syncthreads();

  const int ucol = wg * 48;

  for (int s = 0; s < TC; ++s) {
    const int t  = dir ? (T_ - 1 - chunk * TC - s) : (chunk * TC + s);
    const int lt = dir ? (TC - 1 - s) : s;
    const unsigned seq = seqBase + (unsigned)s + 1u;
    const int par = (s + 1) & 1;

    // ---- prefetch pre-activations (owner threads; L2 latency under matvec) ----
    float pv0, pv1, pv2, pv3;
    if (tid < 192) {
      const size_t pbase = ((size_t)(bg * 4 + own_b) * TC + lt) * G4 + ucol + own_u;
      pv0 = pre[pbase];           pv1 = pre[pbase + H_];
      pv2 = pre[pbase + 2 * H_];  pv3 = pre[pbase + 3 * H_];
    }

    // ---- matvec: acc[r][b] over this thread's 24-k slice ----
    float acc[12][4];
    #pragma unroll
    for (int r = 0; r < 12; ++r)
      #pragma unroll
      for (int b = 0; b < 4; ++b) acc[r][b] = 0.f;

    const int hcol = ks * 28;
    #pragma unroll
    for (int kq = 0; kq < 6; ++kq) {
      f32x4 h4[4];
      #pragma unroll
      for (int b = 0; b < 4; ++b)
        h4[b] = *(const f32x4*)&h_lds[b * 448 + hcol + kq * 4];
      #pragma unroll
      for (int r = 0; r < 12; ++r) {
        f32x4 w4 = W[r][kq];
        #pragma unroll
        for (int b = 0; b < 4; ++b)
          acc[r][b] += w4.x * h4[b].x + w4.y * h4[b].y
                     + w4.z * h4[b].z + w4.w * h4[b].w;
      }
    }

    // ---- per-row butterfly over the 16 ks lanes (4 batch values each) ----
    // masks {8,4}: halve 4->1 (batch = ((ks>>3)&1)*2 + ((ks>>2)&1));
    // masks {2,1}: duplicate-sum; lanes ks&3==0 write gLDS.
    const bool up8 = (ks & 8) != 0;
    const bool up4 = (ks & 4) != 0;
    const int bsel = ((ks >> 3) & 1) * 2 + ((ks >> 2) & 1);
    #pragma unroll
    for (int r = 0; r < 12; ++r) {
      float s0 = up8 ? acc[r][0] : acc[r][2];
      float s1 = up8 ? acc[r][1] : acc[r][3];
      float r0 = __shfl_xor(s0, 8, 64);
      float r1 = __shfl_xor(s1, 8, 64);
      float a0 = (up8 ? acc[r][2] : acc[r][0]) + r0;
      float a1 = (up8 ? acc[r][3] : acc[r][1]) + r1;
      float ss = up4 ? a0 : a1;
      float rr = __shfl_xor(ss, 4, 64);
      float v  = (up4 ? a1 : a0) + rr;
      v += __shfl_xor(v, 2, 64);
      v += __shfl_xor(v, 1, 64);
      if ((ks & 3) == 0)
        gLDS[g * 192 + (ug * 12 + r) * 4 + bsel] = v;
    }
    __syncthreads();

    // ---- nonlinearity + publish (sc0 sc1, no fence) ----
    if (tid < 192) {
      float gi = sigm(gLDS[0 * 192 + own_u * 4 + own_b] + pv0);
      float gf = sigm(gLDS[1 * 192 + own_u * 4 + own_b] + pv1);
      float gg = tanhf(gLDS[2 * 192 + own_u * 4 + own_b] + pv2);
      float go = sigm(gLDS[3 * 192 + own_u * 4 + own_b] + pv3);
      c_own = gf * c_own + gi * gg;
      float h_new = go * tanhf(c_own);

      float* hg_w = par ? hg1 : hg0;
      asm volatile("global_store_dword %0, %1, off sc0 sc1"
                   :: "v"(hg_w + own_b * 384 + ucol + own_u), "v"(h_new) : "memory");

      const int bglob = bg * 4 + own_b;
      if (LAYER == 0)
        hbuf[((size_t)bglob * T_ + t) * 768 + dir * H_ + ucol + own_u] = h_new;
      else
        (dir ? h2cB : h2cF)[((size_t)bglob * TC + lt) * H_ + ucol + own_u] = h_new;
    }
    asm volatile("s_waitcnt vmcnt(0)" ::: "memory");   // h stores at coherence pt
    __syncthreads();                                   // all waves ack'd
    if (tid == 0)
      asm volatile("global_store_dword %0, %1, off sc0 sc1"
                   :: "v"(&flags[stream * 8 + wg]), "v"(seq) : "memory");
    if (s == TC - 1) break;   // next launch syncs via kernel boundary

    // ---- spin: one lane per WG-flag of this 8-WG community ----
    if (tid < 8) {
      const unsigned* fp = &flags[stream * 8 + tid];
      unsigned v;
      while (true) {
        asm volatile("global_load_dword %0, %1, off sc0 sc1\n\ts_waitcnt vmcnt(0)"
                     : "=v"(v) : "v"(fp) : "memory");
        if (v >= seq) break;
        __builtin_amdgcn_s_sleep(1);
      }
    }
    __syncthreads();

    // ---- reload h (6KB: 384 f4 over 256 threads) ----
    {
      const float* src = par ? hg1 : hg0;
      f32x4 tmp0, tmp1;
      {
        int f = tid;
        int b = f / 96, k4 = (f % 96) * 4;
        asm volatile("global_load_dwordx4 %0, %1, off sc0 sc1"
                     : "=v"(tmp0) : "v"(src + b * 384 + k4) : "memory");
      }
      if (tid < 128) {
        int f = tid + 256;
        int b = f / 96, k4 = (f % 96) * 4;
        asm volatile("global_load_dwordx4 %0, %1, off sc0 sc1"
                     : "=v"(tmp1) : "v"(src + b * 384 + k4) : "memory");
      }
      asm volatile("s_waitcnt vmcnt(0)" ::: "memory");
      __builtin_amdgcn_sched_barrier(0);
      {
        int f = tid;
        int b = f / 96, k4 = (f % 96) * 4;
        *(f32x4*)&h_lds[b * 448 + (k4 / 24) * 28 + (k4 % 24)] = tmp0;
      }
      if (tid < 128) {
        int f = tid + 256;
        int b = f / 96, k4 = (f % 96) * 4;
        *(f32x4*)&h_lds[b * 448 + (k4 / 24) * 28 + (k4 % 24)] = tmp1;
      }
    }
    __syncthreads();
  }

  if (tid < 192)
    c_g[(size_t)(stream * 8 + wg) * 192 + tid] = c_own;
}

// ---------------- feats init: feats[row][n] = fc_b[n] ------------------------
__global__ __launch_bounds__(256)
void feats_init(const float* __restrict__ fc_b, float* __restrict__ feats) {
  const int n = threadIdx.x & 31;
  const size_t row = (size_t)blockIdx.x * 8 + (threadIdx.x >> 5);
  if (n >= NTAGS) return;
  feats[row * NTAGS + n] = fc_b[n];
}

// -------- half-FC accumulate (z picks fwd/bwd): feats += h2c @ fc_w_half^T ---
__global__ __launch_bounds__(256)
void fc_half(const float* __restrict__ h2cF, const float* __restrict__ h2cB,
             const float* __restrict__ fc_w,
             float* __restrict__ feats, int t0f, int t0b) {
  const int z = blockIdx.z;
  const float* __restrict__ h2c = z ? h2cB : h2cF;
  const int coff = z ? H_ : 0;
  const int t0   = z ? t0b : t0f;

  const int tid = threadIdx.x;
  const int n  = tid & 31;
  const int rl = tid >> 5;
  const int row_loc = blockIdx.x * 8 + rl;     // 0..4095
  if (n >= NTAGS) return;
  const int b  = row_loc >> 6;
  const int lt = row_loc & 63;
  const float* x = h2c + (size_t)row_loc * H_;
  const float* w = fc_w + (size_t)n * D_ + coff;
  float acc = 0.f;
  #pragma unroll 8
  for (int k = 0; k < H_; k += 4) {
    float4 xv = *(const float4*)(x + k);
    float4 wv = *(const float4*)(w + k);
    acc += xv.x * wv.x + xv.y * wv.y + xv.z * wv.z + xv.w * wv.w;
  }
  feats[((size_t)b * T_ + t0 + lt) * NTAGS + n] += acc;
}

// ---------------- Viterbi: one wave per batch element -----------------------
__global__ __launch_bounds__(64)
void viterbi_kernel(const float* __restrict__ feats,
                    const float* __restrict__ trans,
                    float* __restrict__ score_out, float* __restrict__ path_out) {
  const int b = blockIdx.x;
  const int lane = threadIdx.x;
  __shared__ float trs[NTAGS * NTAGS];
  __shared__ float ld[32];
  __shared__ unsigned char psi[T_ - 1][NTAGS];

  for (int i = lane; i < NTAGS * NTAGS; i += 64) trs[i] = trans[i];
  if (lane < NTAGS) ld[lane] = -10000.0f;
  __syncthreads();

  for (int t = 1; t < T_; ++t) {
    float best = -INFINITY; int arg = 0;
    if (lane < NTAGS) {
      #pragma unroll
      for (int p = 0; p < NTAGS; ++p) {
        float v = trs[lane * NTAGS + p] + ld[p];
        if (v > best) { best = v; arg = p; }   // first-occurrence argmax
      }
    }
    __syncthreads();
    if (lane < NTAGS) {
      ld[lane] = best + feats[((size_t)b * T_ + t) * NTAGS + lane];
      psi[t - 1][lane] = (unsigned char)arg;
    }
    __syncthreads();
  }

  if (lane == 0) {
    float best = ld[0]; int last = 0;
    #pragma unroll
    for (int p = 1; p < NTAGS; ++p)
      if (ld[p] > best) { best = ld[p]; last = p; }
    score_out[b] = best;
    int tag = last;
    path_out[(size_t)b * T_ + (T_ - 1)] = (float)tag;
    for (int t = T_ - 2; t >= 0; --t) {
      tag = psi[t][tag];
      path_out[(size_t)b * T_ + t] = (float)tag;
    }
  }
}

// ---------------------------------------------------------------------------
extern "C" void kernel_launch(void* const* d_in, const int* in_sizes, int n_in,
                              void* d_out, int out_size, void* d_ws, size_t ws_size,
                              hipStream_t stream) {
  const float* embeds = (const float*)d_in[0];
  const float* trans  = (const float*)d_in[1];
  const float* fc_w   = (const float*)d_in[2];
  const float* fc_b   = (const float*)d_in[3];
  const float* w_ih[2][2] = {{(const float*)d_in[4],  (const float*)d_in[8]},
                             {(const float*)d_in[12], (const float*)d_in[16]}};
  const float* w_hh[2][2] = {{(const float*)d_in[5],  (const float*)d_in[9]},
                             {(const float*)d_in[13], (const float*)d_in[17]}};
  const float* b_ih[2][2] = {{(const float*)d_in[6],  (const float*)d_in[10]},
                             {(const float*)d_in[14], (const float*)d_in[18]}};
  const float* b_hh[2][2] = {{(const float*)d_in[7],  (const float*)d_in[11]},
                             {(const float*)d_in[15], (const float*)d_in[19]}};

  const size_t HB   = (size_t)B_ * T_ * 768;     // 25,165,824 (h1)
  const size_t PRE  = (size_t)B_ * TC * G4;      //  6,291,456 each
  const size_t H2C  = (size_t)B_ * TC * H_;      //  1,572,864 each
  const size_t FT   = (size_t)B_ * T_ * NTAGS;   //    983,040
  const size_t HG   = (size_t)2 * 32 * 1536;     //     98,304
  const size_t CG   = (size_t)32 * 8 * 192;      //     49,152

  float* ws     = (float*)d_ws;
  float* hbuf   = ws;
  float* preF   = hbuf + HB;
  float* preB   = preF + PRE;
  float* h2cF   = preB + PRE;
  float* h2cB   = h2cF + H2C;
  float* feats  = h2cB + H2C;
  float* h_g    = feats + FT;
  float* c_g    = h_g + HG;
  unsigned* flags = (unsigned*)(c_g + CG);       // 512 u32 (256 used + pad)

  hipMemsetAsync(flags, 0, 512 * sizeof(unsigned), stream);
  feats_init<<<(B_ * T_) / 8, 256, 0, stream>>>(fc_b, feats);

  dim3 gg(G4 / 128, (B_ * TC) / 128, 2);         // (12, 32, 2) = 768 WGs

  // -------- layer 0 --------
  for (int c = 0; c < NCH; ++c) {
    const int t0f = c * TC;
    const int t0b = T_ - (c + 1) * TC;
    sgemm_pre<<<gg, 256, 0, stream>>>(embeds, t0f, t0b, w_ih[0][0], w_ih[0][1],
                                      b_ih[0][0], b_hh[0][0], b_ih[0][1], b_hh[0][1],
                                      preF, preB);
    lstm_chunk<0><<<256, 256, 0, stream>>>(preF, preB, w_hh[0][0], w_hh[0][1],
                                           hbuf, nullptr, nullptr, h_g, c_g,
                                           flags, c, (unsigned)(c * TC));
  }

  // -------- layer 1 (+ per-chunk half-FC) --------
  for (int c = 0; c < NCH; ++c) {
    const int t0f = c * TC;
    const int t0b = T_ - (c + 1) * TC;
    sgemm_pre<<<gg, 256, 0, stream>>>(hbuf, t0f, t0b, w_ih[1][0], w_ih[1][1],
                                      b_ih[1][0], b_hh[1][0], b_ih[1][1], b_hh[1][1],
                                      preF, preB);
    lstm_chunk<1><<<256, 256, 0, stream>>>(preF, preB, w_hh[1][0], w_hh[1][1],
                                           nullptr, h2cF, h2cB, h_g, c_g,
                                           flags, c, (unsigned)(T_ + c * TC));
    dim3 gf((B_ * TC) / 8, 1, 2);
    fc_half<<<gf, 256, 0, stream>>>(h2cF, h2cB, fc_w, feats, t0f, t0b);
  }

  // -------- Viterbi -> d_out = [score(64) | path(64*512) as float] --------
  float* score = (float*)d_out;
  float* path  = score + B_;
  viterbi_kernel<<<B_, 64, 0, stream>>>(feats, trans, score, path);
}

// Round 9
// 11179.067 us; speedup vs baseline: 1.0270x; 1.0270x over previous
//
#include <hip/hip_runtime.h>
#include <math.h>

// ---------------------------------------------------------------------------
// Bert_BiLstm_Crf: 2-layer BiLSTM (B=64,T=512,D=768,H=384/dir) -> FC(30) -> Viterbi
// Round 9: tagged {h,tag} pair sync (round-5 protocol, proven exact) at
// community=8 (12KB polls), W-in-VGPR matvec (round-8 tile, audited), TC=128.
// Chain per step: publish pairs -> poll data+tags (equality) -> LDS fill.
// No vmcnt ack, no flags, 2 barriers/step.
// ---------------------------------------------------------------------------

#define B_    64
#define T_    512
#define D_    768
#define H_    384
#define G4    1536
#define NTAGS 30
#define TC    128
#define NCH   (T_ / TC)     // 4

typedef float f32x4 __attribute__((ext_vector_type(4)));
typedef float f32x2 __attribute__((ext_vector_type(2)));

__device__ __forceinline__ float sigm(float x) { return 1.f / (1.f + expf(-x)); }

// ------------- chunk GEMM (z picks fwd/bwd): pre = A_chunk @ W^T + b1 + b2 --
__global__ __launch_bounds__(256)
void sgemm_pre(const float* __restrict__ A, int t0f, int t0b,
               const float* __restrict__ Wf, const float* __restrict__ Wb,
               const float* __restrict__ b1f, const float* __restrict__ b2f,
               const float* __restrict__ b1b, const float* __restrict__ b2b,
               float* __restrict__ outF, float* __restrict__ outB) {
  const int z = blockIdx.z;
  const int t0 = z ? t0b : t0f;
  const float* __restrict__ W  = z ? Wb  : Wf;
  const float* __restrict__ b1 = z ? b1b : b1f;
  const float* __restrict__ b2 = z ? b2b : b2f;
  float* __restrict__ Cc = z ? outB : outF;

  __shared__ float As[16][128];
  __shared__ float Bs[16][128];
  const int tid = threadIdx.x;
  const int bm = blockIdx.y * 128;
  const int bn = blockIdx.x * 128;
  const int tx = tid & 15;
  const int ty = tid >> 4;

  float acc[8][8];
  #pragma unroll
  for (int i = 0; i < 8; ++i)
    #pragma unroll
    for (int j = 0; j < 8; ++j) acc[i][j] = 0.f;

  for (int k0 = 0; k0 < D_; k0 += 16) {
    #pragma unroll
    for (int s = tid; s < 512; s += 256) {
      int r = s >> 2, k4 = (s & 3) * 4;
      int rl = bm + r;
      const float* arow = A + ((size_t)(rl / TC) * T_ + t0 + (rl % TC)) * D_;
      float4 va = *(const float4*)(arow + k0 + k4);
      As[k4 + 0][r] = va.x; As[k4 + 1][r] = va.y;
      As[k4 + 2][r] = va.z; As[k4 + 3][r] = va.w;
      float4 vb = *(const float4*)(W + (size_t)(bn + r) * D_ + k0 + k4);
      Bs[k4 + 0][r] = vb.x; Bs[k4 + 1][r] = vb.y;
      Bs[k4 + 2][r] = vb.z; Bs[k4 + 3][r] = vb.w;
    }
    __syncthreads();
    #pragma unroll
    for (int k = 0; k < 16; ++k) {
      float a[8], bv[8];
      *(float4*)(a)      = *(const float4*)&As[k][ty * 4];
      *(float4*)(a + 4)  = *(const float4*)&As[k][64 + ty * 4];
      *(float4*)(bv)     = *(const float4*)&Bs[k][tx * 4];
      *(float4*)(bv + 4) = *(const float4*)&Bs[k][64 + tx * 4];
      #pragma unroll
      for (int i = 0; i < 8; ++i)
        #pragma unroll
        for (int j = 0; j < 8; ++j)
          acc[i][j] += a[i] * bv[j];
    }
    __syncthreads();
  }

  float4 b1l = *(const float4*)(b1 + bn + tx * 4);
  float4 b2l = *(const float4*)(b2 + bn + tx * 4);
  float4 b1h = *(const float4*)(b1 + bn + 64 + tx * 4);
  float4 b2h = *(const float4*)(b2 + bn + 64 + tx * 4);
  float4 bl = {b1l.x + b2l.x, b1l.y + b2l.y, b1l.z + b2l.z, b1l.w + b2l.w};
  float4 bh = {b1h.x + b2h.x, b1h.y + b2h.y, b1h.z + b2h.z, b1h.w + b2h.w};

  #pragma unroll
  for (int i = 0; i < 8; ++i) {
    int r = (i < 4) ? (ty * 4 + i) : (64 + ty * 4 + (i - 4));
    size_t row = (size_t)(bm + r);
    float4 lo = {acc[i][0] + bl.x, acc[i][1] + bl.y, acc[i][2] + bl.z, acc[i][3] + bl.w};
    float4 hi = {acc[i][4] + bh.x, acc[i][5] + bh.y, acc[i][6] + bh.z, acc[i][7] + bh.w};
    *(float4*)(Cc + row * G4 + bn + tx * 4)      = lo;
    *(float4*)(Cc + row * G4 + bn + 64 + tx * 4) = hi;
  }
}

// ---------------- persistent-W LSTM recurrence chunk ------------------------
// 256 WGs (1/CU). stream = bid&31 -> (dir = s&1, 4-batch group bg = s>>1);
// wg = bid>>5 -> 48 hidden units, W in VGPRs (round-8 tile, audited).
// Cross-WG h exchange: tagged {h,(float)seq} pairs, dwordx2 sc0 sc1 stores;
// readers poll data+tags (equality) directly -- no ack/flag round trips.
template<int LAYER>
__global__ __launch_bounds__(256, 1)
void lstm_chunk(const float* __restrict__ preF, const float* __restrict__ preB,
                const float* __restrict__ whhF, const float* __restrict__ whhB,
                float* __restrict__ hbuf, float* __restrict__ h2cF, float* __restrict__ h2cB,
                float* __restrict__ hpairs, float* __restrict__ c_g,
                int chunk, unsigned seqBase) {
  const int bid    = blockIdx.x;
  const int stream = bid & 31;          // 0..31
  const int wg     = bid >> 5;          // 0..7
  const int dir    = stream & 1;
  const int bg     = stream >> 1;       // 0..15
  const int tid    = threadIdx.x;
  const int g      = tid >> 6;          // gate (wave) 0..3
  const int lane   = tid & 63;
  const int ks     = lane & 15;         // k-slice id (24 k each)
  const int ug     = lane >> 4;         // unit group 0..3 (12 units each)

  const float* __restrict__ pre = dir ? preB : preF;
  const float* __restrict__ whh = dir ? whhB : whhF;

  __shared__ float h_lds[4 * 448];      // [b][16 slices * 28]
  __shared__ float gLDS[4 * 192];       // [gate][u*4 + b]
  __shared__ float lds_pad[18432];      // force 1 WG/CU

  if (__float_as_uint(c_g[0]) == 0xDEADBEEFu) lds_pad[tid] = 1.f;  // keep pad

  // ---- W block in registers: rows g*384 + wg*48 + ug*12 + r, k = ks*24 + j ----
  f32x4 W[12][6];
  {
    const float* wsrc = whh + ((size_t)(g * H_ + wg * 48 + ug * 12)) * H_ + ks * 24;
    #pragma unroll
    for (int r = 0; r < 12; ++r)
      #pragma unroll
      for (int jj = 0; jj < 6; ++jj)
        W[r][jj] = *(const f32x4*)(wsrc + (size_t)r * H_ + jj * 4);
  }

  // gate/c ownership: tid<192 -> (u = tid%48, b = tid/48 in [0,4))
  const int own_u = tid % 48;
  const int own_b = tid / 48;
  float c_own = 0.f;
  if (chunk > 0 && tid < 192)
    c_own = c_g[(size_t)(stream * 8 + wg) * 192 + tid];

  // tagged-pair regions: [parity][stream]: 1536 pairs (4 b x 384 u) = 3072 f
  float* hp0 = hpairs + (size_t)stream * 3072;
  float* hp1 = hpairs + (size_t)(32 + stream) * 3072;

  // reader slice: f4 chunk f = tid + i*256 (i<3) covers pairs 2f, 2f+1
  int ldsoff[3];
  #pragma unroll
  for (int i = 0; i < 3; ++i) {
    int f  = tid + i * 256;
    int b  = f / 192;
    int u0 = 2 * (f % 192);
    ldsoff[i] = b * 448 + (u0 / 24) * 28 + (u0 % 24);
  }

  // ---- init h_lds ----
  if (chunk == 0) {
    for (int i = tid; i < 4 * 448; i += 256) h_lds[i] = 0.f;
  } else {
    const float ftag = (float)(int)seqBase;   // prev chunk's final tag
    f32x4 v[3];
    bool done = false;
    while (!done) {
      #pragma unroll
      for (int i = 0; i < 3; ++i)
        asm volatile("global_load_dwordx4 %0, %1, off sc0 sc1"
                     : "=v"(v[i]) : "v"(hp0 + (size_t)(tid + i * 256) * 4) : "memory");
      asm volatile("s_waitcnt vmcnt(0)" ::: "memory");
      done = true;
      #pragma unroll
      for (int i = 0; i < 3; ++i) done = done && (v[i].y == ftag) && (v[i].w == ftag);
      if (!done) __builtin_amdgcn_s_sleep(1);
    }
    #pragma unroll
    for (int i = 0; i < 3; ++i)
      *(f32x2*)&h_lds[ldsoff[i]] = f32x2{v[i].x, v[i].z};
  }
  __syncthreads();

  const int ucol = wg * 48;

  for (int s = 0; s < TC; ++s) {
    const int t  = dir ? (T_ - 1 - chunk * TC - s) : (chunk * TC + s);
    const int lt = dir ? (TC - 1 - s) : s;
    const float ftag = (float)(int)(seqBase + (unsigned)s + 1u);
    float* hp_w = ((s + 1) & 1) ? hp1 : hp0;

    // ---- prefetch pre-activations (owner threads; latency under matvec) ----
    float pv0, pv1, pv2, pv3;
    if (tid < 192) {
      const size_t pbase = ((size_t)(bg * 4 + own_b) * TC + lt) * G4 + ucol + own_u;
      pv0 = pre[pbase];           pv1 = pre[pbase + H_];
      pv2 = pre[pbase + 2 * H_];  pv3 = pre[pbase + 3 * H_];
    }

    // ---- matvec: acc[r][b] over this thread's 24-k slice ----
    float acc[12][4];
    #pragma unroll
    for (int r = 0; r < 12; ++r)
      #pragma unroll
      for (int b = 0; b < 4; ++b) acc[r][b] = 0.f;

    const int hcol = ks * 28;
    #pragma unroll
    for (int kq = 0; kq < 6; ++kq) {
      f32x4 h4[4];
      #pragma unroll
      for (int b = 0; b < 4; ++b)
        h4[b] = *(const f32x4*)&h_lds[b * 448 + hcol + kq * 4];
      #pragma unroll
      for (int r = 0; r < 12; ++r) {
        f32x4 w4 = W[r][kq];
        #pragma unroll
        for (int b = 0; b < 4; ++b)
          acc[r][b] += w4.x * h4[b].x + w4.y * h4[b].y
                     + w4.z * h4[b].z + w4.w * h4[b].w;
      }
    }

    // ---- per-row butterfly over 16 ks lanes (audited r8 mapping) ----
    const bool up8 = (ks & 8) != 0;
    const bool up4 = (ks & 4) != 0;
    const int bsel = ((ks >> 3) & 1) * 2 + ((ks >> 2) & 1);
    #pragma unroll
    for (int r = 0; r < 12; ++r) {
      float s0 = up8 ? acc[r][0] : acc[r][2];
      float s1 = up8 ? acc[r][1] : acc[r][3];
      float r0 = __shfl_xor(s0, 8, 64);
      float r1 = __shfl_xor(s1, 8, 64);
      float a0 = (up8 ? acc[r][2] : acc[r][0]) + r0;
      float a1 = (up8 ? acc[r][3] : acc[r][1]) + r1;
      float ss = up4 ? a0 : a1;
      float rr = __shfl_xor(ss, 4, 64);
      float v  = (up4 ? a1 : a0) + rr;
      v += __shfl_xor(v, 2, 64);
      v += __shfl_xor(v, 1, 64);
      if ((ks & 3) == 0)
        gLDS[g * 192 + (ug * 12 + r) * 4 + bsel] = v;
    }
    __syncthreads();

    // ---- nonlinearity + tagged publish (no ack, no flag) ----
    if (tid < 192) {
      float gi = sigm(gLDS[0 * 192 + own_u * 4 + own_b] + pv0);
      float gf = sigm(gLDS[1 * 192 + own_u * 4 + own_b] + pv1);
      float gg = tanhf(gLDS[2 * 192 + own_u * 4 + own_b] + pv2);
      float go = sigm(gLDS[3 * 192 + own_u * 4 + own_b] + pv3);
      c_own = gf * c_own + gi * gg;
      float h_new = go * tanhf(c_own);

      f32x2 pv = {h_new, ftag};
      asm volatile("global_store_dwordx2 %0, %1, off sc0 sc1"
                   :: "v"(hp_w + (size_t)(own_b * 384 + ucol + own_u) * 2), "v"(pv)
                   : "memory");

      const int bglob = bg * 4 + own_b;
      if (LAYER == 0)
        hbuf[((size_t)bglob * T_ + t) * 768 + dir * H_ + ucol + own_u] = h_new;
      else
        (dir ? h2cB : h2cF)[((size_t)bglob * TC + lt) * H_ + ucol + own_u] = h_new;
    }
    if (s == TC - 1) break;   // next launch polls these tags

    // ---- poll all tagged pairs of this step, refill h_lds ----
    {
      f32x4 v[3];
      bool done = false;
      while (!done) {
        #pragma unroll
        for (int i = 0; i < 3; ++i)
          asm volatile("global_load_dwordx4 %0, %1, off sc0 sc1"
                       : "=v"(v[i]) : "v"(hp_w + (size_t)(tid + i * 256) * 4) : "memory");
        asm volatile("s_waitcnt vmcnt(0)" ::: "memory");
        done = true;
        #pragma unroll
        for (int i = 0; i < 3; ++i) done = done && (v[i].y == ftag) && (v[i].w == ftag);
        if (!done) __builtin_amdgcn_s_sleep(1);
      }
      #pragma unroll
      for (int i = 0; i < 3; ++i)
        *(f32x2*)&h_lds[ldsoff[i]] = f32x2{v[i].x, v[i].z};
    }
    __syncthreads();
  }

  if (tid < 192)
    c_g[(size_t)(stream * 8 + wg) * 192 + tid] = c_own;
}

// ---------------- feats init: feats[row][n] = fc_b[n] ------------------------
__global__ __launch_bounds__(256)
void feats_init(const float* __restrict__ fc_b, float* __restrict__ feats) {
  const int n = threadIdx.x & 31;
  const size_t row = (size_t)blockIdx.x * 8 + (threadIdx.x >> 5);
  if (n >= NTAGS) return;
  feats[row * NTAGS + n] = fc_b[n];
}

// -------- half-FC accumulate (z picks fwd/bwd): feats += h2c @ fc_w_half^T ---
__global__ __launch_bounds__(256)
void fc_half(const float* __restrict__ h2cF, const float* __restrict__ h2cB,
             const float* __restrict__ fc_w,
             float* __restrict__ feats, int t0f, int t0b) {
  const int z = blockIdx.z;
  const float* __restrict__ h2c = z ? h2cB : h2cF;
  const int coff = z ? H_ : 0;
  const int t0   = z ? t0b : t0f;

  const int tid = threadIdx.x;
  const int n  = tid & 31;
  const int rl = tid >> 5;
  const int row_loc = blockIdx.x * 8 + rl;     // 0..B_*TC-1
  if (n >= NTAGS) return;
  const int b  = row_loc / TC;
  const int lt = row_loc % TC;
  const float* x = h2c + (size_t)row_loc * H_;
  const float* w = fc_w + (size_t)n * D_ + coff;
  float acc = 0.f;
  #pragma unroll 8
  for (int k = 0; k < H_; k += 4) {
    float4 xv = *(const float4*)(x + k);
    float4 wv = *(const float4*)(w + k);
    acc += xv.x * wv.x + xv.y * wv.y + xv.z * wv.z + xv.w * wv.w;
  }
  feats[((size_t)b * T_ + t0 + lt) * NTAGS + n] += acc;
}

// ---------------- Viterbi: one wave per batch element -----------------------
__global__ __launch_bounds__(64)
void viterbi_kernel(const float* __restrict__ feats,
                    const float* __restrict__ trans,
                    float* __restrict__ score_out, float* __restrict__ path_out) {
  const int b = blockIdx.x;
  const int lane = threadIdx.x;
  __shared__ float trs[NTAGS * NTAGS];
  __shared__ float ld[32];
  __shared__ unsigned char psi[T_ - 1][NTAGS];

  for (int i = lane; i < NTAGS * NTAGS; i += 64) trs[i] = trans[i];
  if (lane < NTAGS) ld[lane] = -10000.0f;
  __syncthreads();

  for (int t = 1; t < T_; ++t) {
    float best = -INFINITY; int arg = 0;
    if (lane < NTAGS) {
      #pragma unroll
      for (int p = 0; p < NTAGS; ++p) {
        float v = trs[lane * NTAGS + p] + ld[p];
        if (v > best) { best = v; arg = p; }   // first-occurrence argmax
      }
    }
    __syncthreads();
    if (lane < NTAGS) {
      ld[lane] = best + feats[((size_t)b * T_ + t) * NTAGS + lane];
      psi[t - 1][lane] = (unsigned char)arg;
    }
    __syncthreads();
  }

  if (lane == 0) {
    float best = ld[0]; int last = 0;
    #pragma unroll
    for (int p = 1; p < NTAGS; ++p)
      if (ld[p] > best) { best = ld[p]; last = p; }
    score_out[b] = best;
    int tag = last;
    path_out[(size_t)b * T_ + (T_ - 1)] = (float)tag;
    for (int t = T_ - 2; t >= 0; --t) {
      tag = psi[t][tag];
      path_out[(size_t)b * T_ + t] = (float)tag;
    }
  }
}

// ---------------------------------------------------------------------------
extern "C" void kernel_launch(void* const* d_in, const int* in_sizes, int n_in,
                              void* d_out, int out_size, void* d_ws, size_t ws_size,
                              hipStream_t stream) {
  const float* embeds = (const float*)d_in[0];
  const float* trans  = (const float*)d_in[1];
  const float* fc_w   = (const float*)d_in[2];
  const float* fc_b   = (const float*)d_in[3];
  const float* w_ih[2][2] = {{(const float*)d_in[4],  (const float*)d_in[8]},
                             {(const float*)d_in[12], (const float*)d_in[16]}};
  const float* w_hh[2][2] = {{(const float*)d_in[5],  (const float*)d_in[9]},
                             {(const float*)d_in[13], (const float*)d_in[17]}};
  const float* b_ih[2][2] = {{(const float*)d_in[6],  (const float*)d_in[10]},
                             {(const float*)d_in[14], (const float*)d_in[18]}};
  const float* b_hh[2][2] = {{(const float*)d_in[7],  (const float*)d_in[11]},
                             {(const float*)d_in[15], (const float*)d_in[19]}};

  const size_t HB   = (size_t)B_ * T_ * 768;     // 25,165,824 (h1)
  const size_t PRE  = (size_t)B_ * TC * G4;      // 12,582,912 each
  const size_t H2C  = (size_t)B_ * TC * H_;      //  3,145,728 each
  const size_t FT   = (size_t)B_ * T_ * NTAGS;   //    983,040
  const size_t HP   = (size_t)2 * 32 * 3072;     //    196,608 (tagged pairs)
  const size_t CG   = (size_t)32 * 8 * 192;      //     49,152

  float* ws     = (float*)d_ws;
  float* hbuf   = ws;
  float* preF   = hbuf + HB;
  float* preB   = preF + PRE;
  float* h2cF   = preB + PRE;
  float* h2cB   = h2cF + H2C;
  float* feats  = h2cB + H2C;
  float* hpairs = feats + FT;
  float* c_g    = hpairs + HP;

  feats_init<<<(B_ * T_) / 8, 256, 0, stream>>>(fc_b, feats);

  dim3 gg(G4 / 128, (B_ * TC) / 128, 2);         // (12, 64, 2) = 1536 WGs

  // -------- layer 0 --------
  for (int c = 0; c < NCH; ++c) {
    const int t0f = c * TC;
    const int t0b = T_ - (c + 1) * TC;
    sgemm_pre<<<gg, 256, 0, stream>>>(embeds, t0f, t0b, w_ih[0][0], w_ih[0][1],
                                      b_ih[0][0], b_hh[0][0], b_ih[0][1], b_hh[0][1],
                                      preF, preB);
    lstm_chunk<0><<<256, 256, 0, stream>>>(preF, preB, w_hh[0][0], w_hh[0][1],
                                           hbuf, nullptr, nullptr, hpairs, c_g,
                                           c, (unsigned)(c * TC));
  }

  // -------- layer 1 (+ per-chunk half-FC) --------
  for (int c = 0; c < NCH; ++c) {
    const int t0f = c * TC;
    const int t0b = T_ - (c + 1) * TC;
    sgemm_pre<<<gg, 256, 0, stream>>>(hbuf, t0f, t0b, w_ih[1][0], w_ih[1][1],
                                      b_ih[1][0], b_hh[1][0], b_ih[1][1], b_hh[1][1],
                                      preF, preB);
    lstm_chunk<1><<<256, 256, 0, stream>>>(preF, preB, w_hh[1][0], w_hh[1][1],
                                           nullptr, h2cF, h2cB, hpairs, c_g,
                                           c, (unsigned)(T_ + c * TC));
    dim3 gf((B_ * TC) / 8, 1, 2);
    fc_half<<<gf, 256, 0, stream>>>(h2cF, h2cB, fc_w, feats, t0f, t0b);
  }

  // -------- Viterbi -> d_out = [score(64) | path(64*512) as float] --------
  float* score = (float*)d_out;
  float* path  = score + B_;
  viterbi_kernel<<<B_, 64, 0, stream>>>(feats, trans, score, path);
}

// Round 10
// 9275.559 us; speedup vs baseline: 1.2378x; 1.2052x over previous
//
#include <hip/hip_runtime.h>
#include <math.h>

// ---------------------------------------------------------------------------
// Bert_BiLstm_Crf: 2-layer BiLSTM (B=64,T=512,D=768,H=384/dir) -> FC(30) -> Viterbi
// Round 10: fused launch = 256 recurrence WGs (round-4 verbatim protocol,
// community 32, W 72f in VGPRs) + 768 GEMM WGs computing NEXT chunk's pre.
// GEMM hides under the recurrence's sync-wait idle time; consumed across the
// kernel boundary (no intra-launch dependency). TC=64.
// ---------------------------------------------------------------------------

#define B_    64
#define T_    512
#define D_    768
#define H_    384
#define G4    1536
#define NTAGS 30
#define TC    64
#define NCH   (T_ / TC)     // 8

typedef float f32x4 __attribute__((ext_vector_type(4)));

__device__ __forceinline__ float sigm(float x) { return 1.f / (1.f + expf(-x)); }

// ---------------- GEMM body (shared by standalone + fused paths) ------------
// Computes pre rows [b*TC+lt][1536] = A[b*T + t0 + lt][:768] @ W^T + b1 + b2
// for one 128x128 tile. smem: As = smem[0..2047], Bs = smem[2048..4095].
__device__ __forceinline__
void gemm_tile(float* __restrict__ smem,
               const float* __restrict__ A, int t0,
               const float* __restrict__ W,
               const float* __restrict__ b1, const float* __restrict__ b2,
               float* __restrict__ Cc, int gx, int gy) {
  float* As = smem;
  float* Bs = smem + 2048;
  const int tid = threadIdx.x;
  const int bm = gy * 128;
  const int bn = gx * 128;
  const int tx = tid & 15;
  const int ty = tid >> 4;

  float acc[8][8];
  #pragma unroll
  for (int i = 0; i < 8; ++i)
    #pragma unroll
    for (int j = 0; j < 8; ++j) acc[i][j] = 0.f;

  for (int k0 = 0; k0 < D_; k0 += 16) {
    #pragma unroll
    for (int s = tid; s < 512; s += 256) {
      int r = s >> 2, k4 = (s & 3) * 4;
      int rl = bm + r;
      const float* arow = A + ((size_t)(rl >> 6) * T_ + t0 + (rl & 63)) * D_;
      float4 va = *(const float4*)(arow + k0 + k4);
      As[(k4 + 0) * 128 + r] = va.x; As[(k4 + 1) * 128 + r] = va.y;
      As[(k4 + 2) * 128 + r] = va.z; As[(k4 + 3) * 128 + r] = va.w;
      float4 vb = *(const float4*)(W + (size_t)(bn + r) * D_ + k0 + k4);
      Bs[(k4 + 0) * 128 + r] = vb.x; Bs[(k4 + 1) * 128 + r] = vb.y;
      Bs[(k4 + 2) * 128 + r] = vb.z; Bs[(k4 + 3) * 128 + r] = vb.w;
    }
    __syncthreads();
    #pragma unroll
    for (int k = 0; k < 16; ++k) {
      float a[8], bv[8];
      *(float4*)(a)      = *(const float4*)&As[k * 128 + ty * 4];
      *(float4*)(a + 4)  = *(const float4*)&As[k * 128 + 64 + ty * 4];
      *(float4*)(bv)     = *(const float4*)&Bs[k * 128 + tx * 4];
      *(float4*)(bv + 4) = *(const float4*)&Bs[k * 128 + 64 + tx * 4];
      #pragma unroll
      for (int i = 0; i < 8; ++i)
        #pragma unroll
        for (int j = 0; j < 8; ++j)
          acc[i][j] += a[i] * bv[j];
    }
    __syncthreads();
  }

  float4 b1l = *(const float4*)(b1 + bn + tx * 4);
  float4 b2l = *(const float4*)(b2 + bn + tx * 4);
  float4 b1h = *(const float4*)(b1 + bn + 64 + tx * 4);
  float4 b2h = *(const float4*)(b2 + bn + 64 + tx * 4);
  float4 bl = {b1l.x + b2l.x, b1l.y + b2l.y, b1l.z + b2l.z, b1l.w + b2l.w};
  float4 bh = {b1h.x + b2h.x, b1h.y + b2h.y, b1h.z + b2h.z, b1h.w + b2h.w};

  #pragma unroll
  for (int i = 0; i < 8; ++i) {
    int r = (i < 4) ? (ty * 4 + i) : (64 + ty * 4 + (i - 4));
    size_t row = (size_t)(bm + r);
    float4 lo = {acc[i][0] + bl.x, acc[i][1] + bl.y, acc[i][2] + bl.z, acc[i][3] + bl.w};
    float4 hi = {acc[i][4] + bh.x, acc[i][5] + bh.y, acc[i][6] + bh.z, acc[i][7] + bh.w};
    *(float4*)(Cc + row * G4 + bn + tx * 4)      = lo;
    *(float4*)(Cc + row * G4 + bn + 64 + tx * 4) = hi;
  }
}

// ------------- standalone chunk GEMM (z picks fwd/bwd) ----------------------
__global__ __launch_bounds__(256)
void sgemm_pre(const float* __restrict__ A, int t0f, int t0b,
               const float* __restrict__ Wf, const float* __restrict__ Wb,
               const float* __restrict__ b1f, const float* __restrict__ b2f,
               const float* __restrict__ b1b, const float* __restrict__ b2b,
               float* __restrict__ outF, float* __restrict__ outB) {
  __shared__ float smem[4096];
  const int z = blockIdx.z;
  gemm_tile(smem, A, z ? t0b : t0f, z ? Wb : Wf,
            z ? b1b : b1f, z ? b2b : b2f,
            z ? outB : outF, blockIdx.x, blockIdx.y);
}

// ---------------- fused: recurrence (bid<256) + next-chunk GEMM -------------
// Recurrence: round-4 verbatim. 8 streams (dir x 16-batch group) x 32 WGs
// (12 units each, W 72f in VGPRs). sc0 sc1 publish -> vmcnt ack -> flag ->
// poll 32 flags -> reload 24KB. GEMM WGs (bid>=256): 12 x 32 x 2 tiles of
// next chunk's pre, consumed by the NEXT launch (kernel-boundary ordering).
template<int LAYER, bool GEMM_NEXT>
__global__ __launch_bounds__(256, 2)
void fused_chunk(const float* __restrict__ preF, const float* __restrict__ preB,
                 float* __restrict__ preFw, float* __restrict__ preBw,
                 const float* __restrict__ gemmA, int t0f_n, int t0b_n,
                 const float* __restrict__ wihF, const float* __restrict__ wihB,
                 const float* __restrict__ bihF, const float* __restrict__ bhhF,
                 const float* __restrict__ bihB, const float* __restrict__ bhhB,
                 const float* __restrict__ whhF, const float* __restrict__ whhB,
                 float* __restrict__ hbuf, float* __restrict__ h2cF, float* __restrict__ h2cB,
                 float* __restrict__ h_g, float* __restrict__ c_g,
                 unsigned* __restrict__ flags, int chunk, unsigned seqBase) {
  __shared__ float smem[7936];          // rec: h_lds 7168 + gLDS 768; gemm: 4096
  const int bid = blockIdx.x;
  const int tid = threadIdx.x;

  if (bid >= 256) {
    if constexpr (GEMM_NEXT) {
      const int gid = bid - 256;        // 0..767
      const int gx = gid % 12;
      const int gy = (gid / 12) % 32;
      const int gz = gid / 384;
      gemm_tile(smem, gemmA, gz ? t0b_n : t0f_n, gz ? wihB : wihF,
                gz ? bihB : bihF, gz ? bhhB : bhhF,
                gz ? preBw : preFw, gx, gy);
    }
    return;
  }

  // ===================== recurrence path (round-4 verbatim) =================
  float* h_lds = smem;                  // 16 * 448
  float* gLDS  = smem + 7168;           // 4 * 192

  const int stream = bid & 7;
  const int wg     = bid >> 3;          // 0..31
  const int dir    = stream & 1;
  const int bg     = stream >> 1;       // 0..3
  const int g      = tid >> 6;          // gate 0..3
  const int lane   = tid & 63;
  const int kg     = lane & 15;         // k-slice id (24 k each)
  const int uq     = lane >> 4;         // 0..3

  const float* __restrict__ pre = dir ? preB : preF;
  const float* __restrict__ whh = dir ? whhB : whhF;

  // ---- W block in registers: rows g*384 + wg*12 + uq*3 + {0,1,2}, k = kg*24.. ----
  float4 W[3][6];
  {
    const float* wsrc = whh + ((size_t)(g * H_ + wg * 12 + uq * 3)) * H_ + kg * 24;
    #pragma unroll
    for (int i = 0; i < 3; ++i)
      #pragma unroll
      for (int jj = 0; jj < 6; ++jj)
        W[i][jj] = *(const float4*)(wsrc + (size_t)i * H_ + jj * 4);
  }

  const int own_u = tid % 12;
  const int own_b = tid / 12;
  float c_own = 0.f;
  if (chunk > 0 && tid < 192)
    c_own = c_g[(((size_t)stream * 32 + wg) * 12 + own_u) * 16 + own_b];

  float* hg0 = h_g + (size_t)stream * 6144;              // parity 0
  float* hg1 = h_g + (size_t)(8 + stream) * 6144;        // parity 1

  // init h_lds (swizzled: col = (k/24)*28 + k%24); cross-launch: plain loads
  if (chunk == 0) {
    for (int i = tid; i < 16 * 448; i += 256) h_lds[i] = 0.f;
  } else {
    #pragma unroll
    for (int i = 0; i < 6; ++i) {
      int f = tid + i * 256;
      int b = f / 96;
      int k4 = (f % 96) * 4;
      float4 v = *(const float4*)(hg0 + b * H_ + k4);
      *(float4*)&h_lds[b * 448 + (k4 / 24) * 28 + (k4 % 24)] = v;
    }
  }
  __syncthreads();

  const int ucol = wg * 12;

  for (int s = 0; s < TC; ++s) {
    const int t  = dir ? (T_ - 1 - chunk * TC - s) : (chunk * TC + s);
    const int lt = dir ? (TC - 1 - s) : s;

    // ---- prefetch pre-activation early (L2 latency hidden under matvec) ----
    float pv0, pv1, pv2;
    {
      const size_t prow = ((size_t)(bg * 16 + kg) * TC + lt) * G4 + g * H_ + ucol + uq * 3;
      pv0 = pre[prow]; pv1 = pre[prow + 1]; pv2 = pre[prow + 2];
    }

    // ---- matvec: acc[i][b] += W_row_i . h[b] over this thread's k-slice ----
    float acc[3][16];
    #pragma unroll
    for (int i = 0; i < 3; ++i)
      #pragma unroll
      for (int b = 0; b < 16; ++b) acc[i][b] = 0.f;

    const int hcol = kg * 28;
    #pragma unroll
    for (int kq = 0; kq < 6; ++kq) {
      #pragma unroll
      for (int b4 = 0; b4 < 4; ++b4) {
        float4 h4[4];
        #pragma unroll
        for (int bb = 0; bb < 4; ++bb)
          h4[bb] = *(const float4*)&h_lds[(b4 * 4 + bb) * 448 + hcol + kq * 4];
        #pragma unroll
        for (int i = 0; i < 3; ++i) {
          float4 w4 = W[i][kq];
          #pragma unroll
          for (int bb = 0; bb < 4; ++bb)
            acc[i][b4 * 4 + bb] += w4.x * h4[bb].x + w4.y * h4[bb].y
                                 + w4.z * h4[bb].z + w4.w * h4[bb].w;
        }
      }
    }

    // ---- butterfly reduce over the 16 kg lanes; lane kg keeps batch kg ----
    float red[3];
    #pragma unroll
    for (int i = 0; i < 3; ++i) {
      int n = 16;
      #pragma unroll
      for (int mask = 8; mask >= 1; mask >>= 1) {
        n >>= 1;
        const bool up = (kg & mask) != 0;
        #pragma unroll
        for (int j = 0; j < n; ++j) {
          float send = up ? acc[i][j] : acc[i][j + n];
          float recv = __shfl_xor(send, mask, 64);
          acc[i][j] = (up ? acc[i][j + n] : acc[i][j]) + recv;
        }
      }
      red[i] = acc[i][0];
    }

    // ---- add pre, exchange gates through LDS ----
    gLDS[g * 192 + (uq * 3 + 0) * 16 + kg] = red[0] + pv0;
    gLDS[g * 192 + (uq * 3 + 1) * 16 + kg] = red[1] + pv1;
    gLDS[g * 192 + (uq * 3 + 2) * 16 + kg] = red[2] + pv2;
    __syncthreads();

    // ---- nonlinearity + publish (system-coherent stores, no fence) ----
    if (tid < 192) {
      float gi = sigm(gLDS[0 * 192 + own_u * 16 + own_b]);
      float gf = sigm(gLDS[1 * 192 + own_u * 16 + own_b]);
      float gg = tanhf(gLDS[2 * 192 + own_u * 16 + own_b]);
      float go = sigm(gLDS[3 * 192 + own_u * 16 + own_b]);
      c_own = gf * c_own + gi * gg;
      float h_new = go * tanhf(c_own);

      float* hg_w = ((s + 1) & 1) ? hg1 : hg0;
      asm volatile("global_store_dword %0, %1, off sc0 sc1"
                   :: "v"(hg_w + own_b * H_ + ucol + own_u), "v"(h_new) : "memory");

      const int bglob = bg * 16 + own_b;
      if (LAYER == 0) {
        hbuf[((size_t)bglob * T_ + t) * 768 + dir * H_ + ucol + own_u] = h_new;
      } else {
        float* o = dir ? h2cB : h2cF;
        o[((size_t)bglob * TC + lt) * H_ + ucol + own_u] = h_new;
      }
    }
    asm volatile("s_waitcnt vmcnt(0)" ::: "memory");   // h stores at coherence pt
    __syncthreads();
    if (tid == 0) {
      unsigned seq = seqBase + (unsigned)s + 1u;
      asm volatile("global_store_dword %0, %1, off sc0 sc1"
                   :: "v"(&flags[stream * 32 + wg]), "v"(seq) : "memory");
    }
    if (s == TC - 1) break;   // last step: next launch syncs via kernel boundary

    // ---- spin: one lane per WG-flag of this stream ----
    if (tid < 32) {
      const unsigned tgt = seqBase + (unsigned)s + 1u;
      const unsigned* fp = &flags[stream * 32 + tid];
      unsigned v;
      while (true) {
        asm volatile("global_load_dword %0, %1, off sc0 sc1\n\ts_waitcnt vmcnt(0)"
                     : "=v"(v) : "v"(fp) : "memory");
        if (v >= tgt) break;
        __builtin_amdgcn_s_sleep(4);
      }
    }
    __syncthreads();

    // ---- refill h_lds from the just-published parity (coherent loads) ----
    {
      const float* src = ((s + 1) & 1) ? hg1 : hg0;
      f32x4 tmp[6];
      #pragma unroll
      for (int i = 0; i < 6; ++i) {
        int f = tid + i * 256;
        int b = f / 96;
        int k4 = (f % 96) * 4;
        asm volatile("global_load_dwordx4 %0, %1, off sc0 sc1"
                     : "=v"(tmp[i]) : "v"(src + b * H_ + k4) : "memory");
      }
      asm volatile("s_waitcnt vmcnt(0)" ::: "memory");
      __builtin_amdgcn_sched_barrier(0);
      #pragma unroll
      for (int i = 0; i < 6; ++i) {
        int f = tid + i * 256;
        int b = f / 96;
        int k4 = (f % 96) * 4;
        *(f32x4*)&h_lds[b * 448 + (k4 / 24) * 28 + (k4 % 24)] = tmp[i];
      }
    }
    __syncthreads();
  }

  if (tid < 192)
    c_g[(((size_t)stream * 32 + wg) * 12 + own_u) * 16 + own_b] = c_own;
}

// ---------------- feats init: feats[row][n] = fc_b[n] ------------------------
__global__ __launch_bounds__(256)
void feats_init(const float* __restrict__ fc_b, float* __restrict__ feats) {
  const int n = threadIdx.x & 31;
  const size_t row = (size_t)blockIdx.x * 8 + (threadIdx.x >> 5);
  if (n >= NTAGS) return;
  feats[row * NTAGS + n] = fc_b[n];
}

// -------- half-FC accumulate (z picks fwd/bwd): feats += h2c @ fc_w_half^T ---
__global__ __launch_bounds__(256)
void fc_half(const float* __restrict__ h2cF, const float* __restrict__ h2cB,
             const float* __restrict__ fc_w,
             float* __restrict__ feats, int t0f, int t0b) {
  const int z = blockIdx.z;
  const float* __restrict__ h2c = z ? h2cB : h2cF;
  const int coff = z ? H_ : 0;
  const int t0   = z ? t0b : t0f;

  const int tid = threadIdx.x;
  const int n  = tid & 31;
  const int rl = tid >> 5;
  const int row_loc = blockIdx.x * 8 + rl;     // 0..4095
  if (n >= NTAGS) return;
  const int b  = row_loc >> 6;
  const int lt = row_loc & 63;
  const float* x = h2c + (size_t)row_loc * H_;
  const float* w = fc_w + (size_t)n * D_ + coff;
  float acc = 0.f;
  #pragma unroll 8
  for (int k = 0; k < H_; k += 4) {
    float4 xv = *(const float4*)(x + k);
    float4 wv = *(const float4*)(w + k);
    acc += xv.x * wv.x + xv.y * wv.y + xv.z * wv.z + xv.w * wv.w;
  }
  feats[((size_t)b * T_ + t0 + lt) * NTAGS + n] += acc;
}

// ---------------- Viterbi: one wave per batch element -----------------------
__global__ __launch_bounds__(64)
void viterbi_kernel(const float* __restrict__ feats,
                    const float* __restrict__ trans,
                    float* __restrict__ score_out, float* __restrict__ path_out) {
  const int b = blockIdx.x;
  const int lane = threadIdx.x;
  __shared__ float trs[NTAGS * NTAGS];
  __shared__ float ld[32];
  __shared__ unsigned char psi[T_ - 1][NTAGS];

  for (int i = lane; i < NTAGS * NTAGS; i += 64) trs[i] = trans[i];
  if (lane < NTAGS) ld[lane] = -10000.0f;
  __syncthreads();

  for (int t = 1; t < T_; ++t) {
    float best = -INFINITY; int arg = 0;
    if (lane < NTAGS) {
      #pragma unroll
      for (int p = 0; p < NTAGS; ++p) {
        float v = trs[lane * NTAGS + p] + ld[p];
        if (v > best) { best = v; arg = p; }   // first-occurrence argmax
      }
    }
    __syncthreads();
    if (lane < NTAGS) {
      ld[lane] = best + feats[((size_t)b * T_ + t) * NTAGS + lane];
      psi[t - 1][lane] = (unsigned char)arg;
    }
    __syncthreads();
  }

  if (lane == 0) {
    float best = ld[0]; int last = 0;
    #pragma unroll
    for (int p = 1; p < NTAGS; ++p)
      if (ld[p] > best) { best = ld[p]; last = p; }
    score_out[b] = best;
    int tag = last;
    path_out[(size_t)b * T_ + (T_ - 1)] = (float)tag;
    for (int t = T_ - 2; t >= 0; --t) {
      tag = psi[t][tag];
      path_out[(size_t)b * T_ + t] = (float)tag;
    }
  }
}

// ---------------------------------------------------------------------------
extern "C" void kernel_launch(void* const* d_in, const int* in_sizes, int n_in,
                              void* d_out, int out_size, void* d_ws, size_t ws_size,
                              hipStream_t stream) {
  const float* embeds = (const float*)d_in[0];
  const float* trans  = (const float*)d_in[1];
  const float* fc_w   = (const float*)d_in[2];
  const float* fc_b   = (const float*)d_in[3];
  const float* w_ih[2][2] = {{(const float*)d_in[4],  (const float*)d_in[8]},
                             {(const float*)d_in[12], (const float*)d_in[16]}};
  const float* w_hh[2][2] = {{(const float*)d_in[5],  (const float*)d_in[9]},
                             {(const float*)d_in[13], (const float*)d_in[17]}};
  const float* b_ih[2][2] = {{(const float*)d_in[6],  (const float*)d_in[10]},
                             {(const float*)d_in[14], (const float*)d_in[18]}};
  const float* b_hh[2][2] = {{(const float*)d_in[7],  (const float*)d_in[11]},
                             {(const float*)d_in[15], (const float*)d_in[19]}};

  const size_t HB   = (size_t)B_ * T_ * 768;     // 25,165,824 (h1)
  const size_t PRE  = (size_t)B_ * TC * G4;      //  6,291,456 each (x4: 2 dirs x 2 parity)
  const size_t H2C  = (size_t)B_ * TC * H_;      //  1,572,864 each
  const size_t FT   = (size_t)B_ * T_ * NTAGS;   //    983,040
  const size_t HG   = (size_t)2 * 8 * 6144;      //     98,304
  const size_t CG   = (size_t)8 * 32 * 12 * 16;  //     49,152

  float* ws     = (float*)d_ws;
  float* hbuf   = ws;
  float* preF[2] = { hbuf + HB,            hbuf + HB + PRE };
  float* preB[2] = { hbuf + HB + 2 * PRE,  hbuf + HB + 3 * PRE };
  float* h2cF   = hbuf + HB + 4 * PRE;
  float* h2cB   = h2cF + H2C;
  float* feats  = h2cB + H2C;
  float* h_g    = feats + FT;
  float* c_g    = h_g + HG;
  unsigned* flags = (unsigned*)(c_g + CG);       // 512 u32

  hipMemsetAsync(flags, 0, 512 * sizeof(unsigned), stream);
  feats_init<<<(B_ * T_) / 8, 256, 0, stream>>>(fc_b, feats);

  dim3 gg(G4 / 128, (B_ * TC) / 128, 2);         // (12, 32, 2) = 768 WGs

  // -------- layer 0 chunk-0 pre (standalone) --------
  sgemm_pre<<<gg, 256, 0, stream>>>(embeds, 0, T_ - TC, w_ih[0][0], w_ih[0][1],
                                    b_ih[0][0], b_hh[0][0], b_ih[0][1], b_hh[0][1],
                                    preF[0], preB[0]);

  // -------- layer 0: fused recurrence + next-chunk GEMM --------
  for (int c = 0; c < NCH; ++c) {
    const int rp = c & 1, wp = (c + 1) & 1;
    const int t0f_n = (c + 1) * TC;
    const int t0b_n = T_ - (c + 2) * TC;
    if (c < NCH - 1)
      fused_chunk<0, true><<<1024, 256, 0, stream>>>(
          preF[rp], preB[rp], preF[wp], preB[wp], embeds, t0f_n, t0b_n,
          w_ih[0][0], w_ih[0][1], b_ih[0][0], b_hh[0][0], b_ih[0][1], b_hh[0][1],
          w_hh[0][0], w_hh[0][1], hbuf, nullptr, nullptr,
          h_g, c_g, flags, c, (unsigned)(c * TC));
    else
      fused_chunk<0, false><<<256, 256, 0, stream>>>(
          preF[rp], preB[rp], nullptr, nullptr, embeds, 0, 0,
          w_ih[0][0], w_ih[0][1], b_ih[0][0], b_hh[0][0], b_ih[0][1], b_hh[0][1],
          w_hh[0][0], w_hh[0][1], hbuf, nullptr, nullptr,
          h_g, c_g, flags, c, (unsigned)(c * TC));
  }

  // -------- layer 1 chunk-0 pre (standalone; needs complete h1) --------
  sgemm_pre<<<gg, 256, 0, stream>>>(hbuf, 0, T_ - TC, w_ih[1][0], w_ih[1][1],
                                    b_ih[1][0], b_hh[1][0], b_ih[1][1], b_hh[1][1],
                                    preF[0], preB[0]);

  // -------- layer 1: fused recurrence + next-chunk GEMM (+ per-chunk FC) ----
  for (int c = 0; c < NCH; ++c) {
    const int rp = c & 1, wp = (c + 1) & 1;
    const int t0f = c * TC;
    const int t0b = T_ - (c + 1) * TC;
    const int t0f_n = (c + 1) * TC;
    const int t0b_n = T_ - (c + 2) * TC;
    if (c < NCH - 1)
      fused_chunk<1, true><<<1024, 256, 0, stream>>>(
          preF[rp], preB[rp], preF[wp], preB[wp], hbuf, t0f_n, t0b_n,
          w_ih[1][0], w_ih[1][1], b_ih[1][0], b_hh[1][0], b_ih[1][1], b_hh[1][1],
          w_hh[1][0], w_hh[1][1], nullptr, h2cF, h2cB,
          h_g, c_g, flags, c, (unsigned)(T_ + c * TC));
    else
      fused_chunk<1, false><<<256, 256, 0, stream>>>(
          preF[rp], preB[rp], nullptr, nullptr, hbuf, 0, 0,
          w_ih[1][0], w_ih[1][1], b_ih[1][0], b_hh[1][0], b_ih[1][1], b_hh[1][1],
          w_hh[1][0], w_hh[1][1], nullptr, h2cF, h2cB,
          h_g, c_g, flags, c, (unsigned)(T_ + c * TC));
    dim3 gf((B_ * TC) / 8, 1, 2);
    fc_half<<<gf, 256, 0, stream>>>(h2cF, h2cB, fc_w, feats, t0f, t0b);
  }

  // -------- Viterbi -> d_out = [score(64) | path(64*512) as float] --------
  float* score = (float*)d_out;
  float* path  = score + B_;
  viterbi_kernel<<<B_, 64, 0, stream>>>(feats, trans, score, path);
}